// Round 1
// baseline (542.147 us; speedup 1.0000x reference)
//
#include <hip/hip_runtime.h>
#include <math.h>

// ---------------------------------------------------------------------------
// GCN: 3x (GEMM -> sym-normalized neighbor aggregate) with SiLU between,
// then per-graph max+mean pool and log_softmax.
// N=100000, E=800000, F_IN=HID=96, C=32, G=128 (derived from sizes at launch).
// ---------------------------------------------------------------------------

static __device__ __forceinline__ float silu_f(float v) {
    return v / (1.0f + __expf(-v));
}

// --- int64-vs-int32 input detection -----------------------------------------
// If indices arrive as int64 (little-endian, values < 2^31), the int32 view is
// [v0,0,v1,0,...] -> odd positions all zero. Random int32 indices make that
// pattern impossible. Deterministic function of the input.
__global__ __launch_bounds__(256) void k_detect(const int* __restrict__ raw,
                                                int* __restrict__ flag) {
    __shared__ int anynz;
    if (threadIdx.x == 0) anynz = 0;
    __syncthreads();
    if (raw[2 * threadIdx.x + 1] != 0) anynz = 1;  // benign race, same value
    __syncthreads();
    if (threadIdx.x == 0) *flag = (anynz ? 0 : 1); // 1 => int64
}

__global__ __launch_bounds__(256) void k_convert(const int* __restrict__ raw,
                                                 int* __restrict__ out,
                                                 const int* __restrict__ flag,
                                                 int count) {
    int i = blockIdx.x * 256 + threadIdx.x;
    if (i < count) out[i] = flag[0] ? raw[2 * i] : raw[i];
}

// --- degree / dinv -----------------------------------------------------------
__global__ __launch_bounds__(256) void k_deg(const int* __restrict__ dst,
                                             int* __restrict__ deg, int E) {
    int e = blockIdx.x * 256 + threadIdx.x;
    if (e < E) atomicAdd(&deg[dst[e]], 1);
}

__global__ __launch_bounds__(256) void k_dinv(const int* __restrict__ deg,
                                              float* __restrict__ dinv, int n) {
    int i = blockIdx.x * 256 + threadIdx.x;
    if (i < n) dinv[i] = rsqrtf((float)deg[i] + 1.0f);  // +1 self loop
}

// --- exclusive scan (3 kernels) ---------------------------------------------
__global__ __launch_bounds__(256) void k_scan1(const int* __restrict__ deg,
                                               int* __restrict__ rowptr,
                                               int* __restrict__ bsum, int n) {
    __shared__ int lds[256];
    int t = threadIdx.x;
    int i = blockIdx.x * 256 + t;
    int v = (i < n) ? deg[i] : 0;
    int orig = v;
    lds[t] = v;
    __syncthreads();
    for (int off = 1; off < 256; off <<= 1) {
        int y = (t >= off) ? lds[t - off] : 0;
        __syncthreads();
        lds[t] += y;
        __syncthreads();
    }
    if (i < n) rowptr[i] = lds[t] - orig;       // exclusive within block
    if (t == 255) bsum[blockIdx.x] = lds[255];  // block total
}

__global__ __launch_bounds__(512) void k_scan2(const int* __restrict__ bsum,
                                               int* __restrict__ boff, int nb) {
    __shared__ int lds[512];
    int t = threadIdx.x;
    int v = (t < nb) ? bsum[t] : 0;
    int orig = v;
    lds[t] = v;
    __syncthreads();
    for (int off = 1; off < 512; off <<= 1) {
        int y = (t >= off) ? lds[t - off] : 0;
        __syncthreads();
        lds[t] += y;
        __syncthreads();
    }
    boff[t] = lds[t] - orig;  // exclusive block offsets
}

__global__ __launch_bounds__(256) void k_scan3(int* __restrict__ rowptr,
                                               const int* __restrict__ boff,
                                               int n, int E) {
    int i = blockIdx.x * 256 + threadIdx.x;
    if (i < n) rowptr[i] += boff[i >> 8];
    if (i == 0) rowptr[n] = E;
}

// --- CSR fill ----------------------------------------------------------------
__global__ __launch_bounds__(256) void k_fill(const int* __restrict__ e32,
                                              const int* __restrict__ rowptr,
                                              int* __restrict__ cursor,
                                              int* __restrict__ adj, int E) {
    int e = blockIdx.x * 256 + threadIdx.x;
    if (e < E) {
        int s = e32[e];
        int d = e32[E + e];
        int p = atomicAdd(&cursor[d], 1);
        adj[rowptr[d] + p] = s;
    }
}

// --- per-graph boundaries (batch is sorted) -----------------------------------
__global__ __launch_bounds__(256) void k_gstart(const int* __restrict__ batch,
                                                int* __restrict__ gstart,
                                                int n, int G) {
    int t = threadIdx.x;
    if (t > G) return;
    int lo = 0, hi = n;
    while (lo < hi) {
        int mid = (lo + hi) >> 1;
        if (batch[mid] < t) lo = mid + 1; else hi = mid;
    }
    gstart[t] = lo;  // lower_bound(batch, t)
}

// --- GEMM: H[n x FOUT] = X[n x 96] @ W[96 x FOUT] ------------------------------
// Block = 256 threads, 64 rows per block. W + x-tile staged in LDS.
// Thread (tx,ty): tx=cols (stride 32), ty=8 row-group; 8 x (FOUT/32) accs.
template <int FOUT>
__global__ __launch_bounds__(256) void k_gemm(const float* __restrict__ X,
                                              const float* __restrict__ W,
                                              float* __restrict__ H, int n) {
    __shared__ float xs[64 * 96];
    __shared__ float wsh[96 * FOUT];
    const int t = threadIdx.x;
    const int row0 = blockIdx.x * 64;

    constexpr int WQ = 96 * FOUT / 4;
    for (int q = t; q < WQ; q += 256)
        ((float4*)wsh)[q] = ((const float4*)W)[q];

    constexpr int XQ = 64 * 96 / 4;  // 1536 float4, tile is contiguous in X
    #pragma unroll
    for (int p = 0; p < XQ / 256; ++p) {
        int q = p * 256 + t;
        int grow = row0 + q / 24;  // 24 float4 per row
        float4 v = make_float4(0.f, 0.f, 0.f, 0.f);
        if (grow < n) v = ((const float4*)X)[(size_t)row0 * 24 + q];
        ((float4*)xs)[q] = v;
    }
    __syncthreads();

    const int tx = t & 31, ty = t >> 5;
    constexpr int NJ = FOUT / 32;
    float acc[8][NJ];
    #pragma unroll
    for (int i = 0; i < 8; i++)
        #pragma unroll
        for (int j = 0; j < NJ; j++) acc[i][j] = 0.f;

    for (int k = 0; k < 96; k += 2) {
        float w0[NJ], w1[NJ];
        #pragma unroll
        for (int j = 0; j < NJ; j++) {
            w0[j] = wsh[k * FOUT + tx + 32 * j];
            w1[j] = wsh[(k + 1) * FOUT + tx + 32 * j];
        }
        #pragma unroll
        for (int i = 0; i < 8; i++) {
            float2 xv = *(const float2*)&xs[(ty * 8 + i) * 96 + k];
            #pragma unroll
            for (int j = 0; j < NJ; j++)
                acc[i][j] += xv.x * w0[j] + xv.y * w1[j];
        }
    }

    #pragma unroll
    for (int i = 0; i < 8; i++) {
        int r = row0 + ty * 8 + i;
        if (r < n) {
            #pragma unroll
            for (int j = 0; j < NJ; j++)
                H[(size_t)r * FOUT + tx + 32 * j] = acc[i][j];
        }
    }
}

// --- aggregation: out[n] = dinv[n]*(sum_{s in adj(n)} dinv[s]*h[s] + dinv[n]*h[n]) + b
// One wave per node. F=96: lane owns f=lane and f=64+(lane&31).
template <int F, bool SILU>
__global__ __launch_bounds__(256) void k_agg(const float* __restrict__ H,
                                             const float* __restrict__ dinv,
                                             const int* __restrict__ rowptr,
                                             const int* __restrict__ adj,
                                             const float* __restrict__ bias,
                                             float* __restrict__ OUT, int n) {
    const int l = threadIdx.x & 63;
    const int node = blockIdx.x * 4 + (threadIdx.x >> 6);
    if (node >= n) return;
    const float dn = dinv[node];
    const int e0 = rowptr[node], e1 = rowptr[node + 1];

    if (F == 96) {
        const int f1 = 64 + (l & 31);
        const float* hb = H + (size_t)node * 96;
        float a0 = dn * hb[l];
        float a1 = dn * hb[f1];
        for (int e = e0; e < e1; ++e) {
            int s = adj[e];
            float ds = dinv[s];
            const float* hs = H + (size_t)s * 96;
            a0 += ds * hs[l];
            a1 += ds * hs[f1];
        }
        float o0 = a0 * dn + bias[l];
        float o1 = a1 * dn + bias[f1];
        if (SILU) { o0 = silu_f(o0); o1 = silu_f(o1); }
        OUT[(size_t)node * 96 + l] = o0;
        if (l < 32) OUT[(size_t)node * 96 + f1] = o1;
    } else {  // F == 32
        const int f = l & 31;
        float a = dn * H[(size_t)node * 32 + f];
        for (int e = e0; e < e1; ++e) {
            int s = adj[e];
            a += dinv[s] * H[(size_t)s * 32 + f];
        }
        float o = a * dn + bias[f];
        if (SILU) o = silu_f(o);
        if (l < 32) OUT[(size_t)node * 32 + f] = o;
    }
}

// --- per-graph max+mean pool (block per graph) --------------------------------
__global__ __launch_bounds__(256) void k_pool(const float* __restrict__ A,
                                              const int* __restrict__ gstart,
                                              float* __restrict__ pooled) {
    int g = blockIdx.x;
    int s0 = gstart[g], s1 = gstart[g + 1];
    int c = threadIdx.x & 31, k = threadIdx.x >> 5;
    float mx = -INFINITY, sm = 0.f;
    for (int nidx = s0 + k; nidx < s1; nidx += 8) {
        float v = A[(size_t)nidx * 32 + c];
        mx = fmaxf(mx, v);
        sm += v;
    }
    __shared__ float smx[8][32], ssm[8][32];
    smx[k][c] = mx;
    ssm[k][c] = sm;
    __syncthreads();
    if (threadIdx.x < 32) {
        float M = smx[0][c], S = ssm[0][c];
        #pragma unroll
        for (int kk = 1; kk < 8; ++kk) {
            M = fmaxf(M, smx[kk][c]);
            S += ssm[kk][c];
        }
        int cnt = s1 - s0;
        pooled[g * 64 + c] = M;
        pooled[g * 64 + 32 + c] = S / fmaxf((float)cnt, 1.0f);
    }
}

// --- row log_softmax over 64 values (one wave per row) -------------------------
__global__ __launch_bounds__(64) void k_lsm(const float* __restrict__ pooled,
                                            float* __restrict__ out) {
    int g = blockIdx.x;
    int l = threadIdx.x;
    float v = pooled[g * 64 + l];
    float m = v;
    #pragma unroll
    for (int o = 32; o > 0; o >>= 1) m = fmaxf(m, __shfl_xor(m, o, 64));
    float e = __expf(v - m);
    float s = e;
    #pragma unroll
    for (int o = 32; o > 0; o >>= 1) s += __shfl_xor(s, o, 64);
    out[g * 64 + l] = v - m - __logf(s);
}

// ---------------------------------------------------------------------------
extern "C" void kernel_launch(void* const* d_in, const int* in_sizes, int n_in,
                              void* d_out, int out_size, void* d_ws, size_t ws_size,
                              hipStream_t stream) {
    const float* x  = (const float*)d_in[0];
    const float* W0 = (const float*)d_in[1];
    const float* b0 = (const float*)d_in[2];
    const float* W1 = (const float*)d_in[3];
    const float* b1 = (const float*)d_in[4];
    const float* W2 = (const float*)d_in[5];
    const float* b2 = (const float*)d_in[6];
    const int* ei_raw    = (const int*)d_in[7];
    const int* batch_raw = (const int*)d_in[8];

    const int N = in_sizes[0] / 96;
    const int E = in_sizes[7] / 2;
    const int G = out_size / 64;
    float* out = (float*)d_out;

    char* ws = (char*)d_ws;
    size_t off = 0;
    auto alloc = [&](size_t bytes) -> void* {
        void* p = ws + off;
        off += (bytes + 255) & ~(size_t)255;
        return p;
    };
    float* bufA    = (float*)alloc((size_t)N * 96 * 4);
    float* bufB    = (float*)alloc((size_t)N * 96 * 4);
    int*   e32     = (int*)alloc((size_t)2 * E * 4);
    int*   batch32 = (int*)alloc((size_t)N * 4);
    int*   deg     = (int*)alloc((size_t)N * 4);
    float* dinv    = (float*)alloc((size_t)N * 4);
    int*   rowptr  = (int*)alloc((size_t)(N + 1) * 4);
    int*   cursor  = (int*)alloc((size_t)N * 4);
    int*   adj     = (int*)alloc((size_t)E * 4);
    int*   bsum    = (int*)alloc(512 * 4);
    int*   boff    = (int*)alloc(512 * 4);
    int*   flag    = (int*)alloc(256);
    int*   gstart  = (int*)alloc((size_t)(G + 1) * 4);
    float* pooled  = (float*)alloc((size_t)G * 64 * 4);
    float* bufC = bufA;                       // N x 32 (aliases bufA, safe)
    float* bufD = bufA + (size_t)N * 32;      // N x 32

    hipMemsetAsync(deg, 0, (size_t)N * 4, stream);
    hipMemsetAsync(cursor, 0, (size_t)N * 4, stream);

    // index dtype normalize
    k_detect<<<1, 256, 0, stream>>>(ei_raw, flag);
    k_convert<<<(2 * E + 255) / 256, 256, 0, stream>>>(ei_raw, e32, flag, 2 * E);
    k_convert<<<(N + 255) / 256, 256, 0, stream>>>(batch_raw, batch32, flag, N);

    // degrees + CSR
    k_deg<<<(E + 255) / 256, 256, 0, stream>>>(e32 + E, deg, E);
    k_dinv<<<(N + 255) / 256, 256, 0, stream>>>(deg, dinv, N);
    int NB = (N + 255) / 256;  // 391 <= 512
    k_scan1<<<NB, 256, 0, stream>>>(deg, rowptr, bsum, N);
    k_scan2<<<1, 512, 0, stream>>>(bsum, boff, NB);
    k_scan3<<<NB, 256, 0, stream>>>(rowptr, boff, N, E);
    k_fill<<<(E + 255) / 256, 256, 0, stream>>>(e32, rowptr, cursor, adj, E);
    k_gstart<<<1, 256, 0, stream>>>(batch32, gstart, N, G);

    const int GB = (N + 63) / 64;
    const int AB = (N + 3) / 4;

    // layer 0
    k_gemm<96><<<GB, 256, 0, stream>>>(x, W0, bufA, N);
    k_agg<96, true><<<AB, 256, 0, stream>>>(bufA, dinv, rowptr, adj, b0, bufB, N);
    // layer 1
    k_gemm<96><<<GB, 256, 0, stream>>>(bufB, W1, bufA, N);
    k_agg<96, true><<<AB, 256, 0, stream>>>(bufA, dinv, rowptr, adj, b1, bufB, N);
    // layer 2
    k_gemm<32><<<GB, 256, 0, stream>>>(bufB, W2, bufC, N);
    k_agg<32, false><<<AB, 256, 0, stream>>>(bufC, dinv, rowptr, adj, b2, bufD, N);

    // pooling + log_softmax
    k_pool<<<G, 256, 0, stream>>>(bufD, gstart, pooled);
    k_lsm<<<G, 64, 0, stream>>>(pooled, out);
}

// Round 2
// 482.267 us; speedup vs baseline: 1.1242x; 1.1242x over previous
//
#include <hip/hip_runtime.h>
#include <hip/hip_fp16.h>
#include <math.h>

// ---------------------------------------------------------------------------
// GCN: 3x (GEMM -> sym-normalized neighbor aggregate) with SiLU between,
// then per-graph max+mean pool and log_softmax.
// Gathered arrays (GEMM outputs) stored fp16 to halve gather traffic;
// all accumulation in fp32.
// ---------------------------------------------------------------------------

static __device__ __forceinline__ float silu_f(float v) {
    return v / (1.0f + __expf(-v));
}

// --- int64-vs-int32 input detection -----------------------------------------
__global__ __launch_bounds__(256) void k_detect(const int* __restrict__ raw,
                                                int* __restrict__ flag) {
    __shared__ int anynz;
    if (threadIdx.x == 0) anynz = 0;
    __syncthreads();
    if (raw[2 * threadIdx.x + 1] != 0) anynz = 1;  // benign race, same value
    __syncthreads();
    if (threadIdx.x == 0) *flag = (anynz ? 0 : 1); // 1 => int64
}

__global__ __launch_bounds__(256) void k_convert(const int* __restrict__ raw,
                                                 int* __restrict__ out,
                                                 const int* __restrict__ flag,
                                                 int count) {
    int i = blockIdx.x * 256 + threadIdx.x;
    if (i < count) out[i] = flag[0] ? raw[2 * i] : raw[i];
}

// --- degree / dinv -----------------------------------------------------------
__global__ __launch_bounds__(256) void k_deg(const int* __restrict__ dst,
                                             int* __restrict__ deg, int E) {
    int e = blockIdx.x * 256 + threadIdx.x;
    if (e < E) atomicAdd(&deg[dst[e]], 1);
}

__global__ __launch_bounds__(256) void k_dinv(const int* __restrict__ deg,
                                              float* __restrict__ dinv, int n) {
    int i = blockIdx.x * 256 + threadIdx.x;
    if (i < n) dinv[i] = rsqrtf((float)deg[i] + 1.0f);  // +1 self loop
}

// --- exclusive scan (3 kernels) ---------------------------------------------
__global__ __launch_bounds__(256) void k_scan1(const int* __restrict__ deg,
                                               int* __restrict__ rowptr,
                                               int* __restrict__ bsum, int n) {
    __shared__ int lds[256];
    int t = threadIdx.x;
    int i = blockIdx.x * 256 + t;
    int v = (i < n) ? deg[i] : 0;
    int orig = v;
    lds[t] = v;
    __syncthreads();
    for (int off = 1; off < 256; off <<= 1) {
        int y = (t >= off) ? lds[t - off] : 0;
        __syncthreads();
        lds[t] += y;
        __syncthreads();
    }
    if (i < n) rowptr[i] = lds[t] - orig;
    if (t == 255) bsum[blockIdx.x] = lds[255];
}

__global__ __launch_bounds__(512) void k_scan2(const int* __restrict__ bsum,
                                               int* __restrict__ boff, int nb) {
    __shared__ int lds[512];
    int t = threadIdx.x;
    int v = (t < nb) ? bsum[t] : 0;
    int orig = v;
    lds[t] = v;
    __syncthreads();
    for (int off = 1; off < 512; off <<= 1) {
        int y = (t >= off) ? lds[t - off] : 0;
        __syncthreads();
        lds[t] += y;
        __syncthreads();
    }
    boff[t] = lds[t] - orig;
}

__global__ __launch_bounds__(256) void k_scan3(int* __restrict__ rowptr,
                                               const int* __restrict__ boff,
                                               int n, int E) {
    int i = blockIdx.x * 256 + threadIdx.x;
    if (i < n) rowptr[i] += boff[i >> 8];
    if (i == 0) rowptr[n] = E;
}

// --- CSR fill ----------------------------------------------------------------
__global__ __launch_bounds__(256) void k_fill(const int* __restrict__ e32,
                                              const int* __restrict__ rowptr,
                                              int* __restrict__ cursor,
                                              int* __restrict__ adj, int E) {
    int e = blockIdx.x * 256 + threadIdx.x;
    if (e < E) {
        int s = e32[e];
        int d = e32[E + e];
        int p = atomicAdd(&cursor[d], 1);
        adj[rowptr[d] + p] = s;
    }
}

// --- per-graph boundaries (batch is sorted) -----------------------------------
__global__ __launch_bounds__(256) void k_gstart(const int* __restrict__ batch,
                                                int* __restrict__ gstart,
                                                int n, int G) {
    int t = threadIdx.x;
    if (t > G) return;
    int lo = 0, hi = n;
    while (lo < hi) {
        int mid = (lo + hi) >> 1;
        if (batch[mid] < t) lo = mid + 1; else hi = mid;
    }
    gstart[t] = lo;
}

// --- GEMM: H[n x FOUT] = X[n x 96] @ W[96 x FOUT], output fp16 ----------------
template <int FOUT>
__global__ __launch_bounds__(256) void k_gemm(const float* __restrict__ X,
                                              const float* __restrict__ W,
                                              __half* __restrict__ H, int n) {
    __shared__ float xs[64 * 96];
    __shared__ float wsh[96 * FOUT];
    const int t = threadIdx.x;
    const int row0 = blockIdx.x * 64;

    constexpr int WQ = 96 * FOUT / 4;
    for (int q = t; q < WQ; q += 256)
        ((float4*)wsh)[q] = ((const float4*)W)[q];

    constexpr int XQ = 64 * 96 / 4;
    #pragma unroll
    for (int p = 0; p < XQ / 256; ++p) {
        int q = p * 256 + t;
        int grow = row0 + q / 24;
        float4 v = make_float4(0.f, 0.f, 0.f, 0.f);
        if (grow < n) v = ((const float4*)X)[(size_t)row0 * 24 + q];
        ((float4*)xs)[q] = v;
    }
    __syncthreads();

    const int tx = t & 31, ty = t >> 5;
    constexpr int NJ = FOUT / 32;
    float acc[8][NJ];
    #pragma unroll
    for (int i = 0; i < 8; i++)
        #pragma unroll
        for (int j = 0; j < NJ; j++) acc[i][j] = 0.f;

    for (int k = 0; k < 96; k += 2) {
        float w0[NJ], w1[NJ];
        #pragma unroll
        for (int j = 0; j < NJ; j++) {
            w0[j] = wsh[k * FOUT + tx + 32 * j];
            w1[j] = wsh[(k + 1) * FOUT + tx + 32 * j];
        }
        #pragma unroll
        for (int i = 0; i < 8; i++) {
            float2 xv = *(const float2*)&xs[(ty * 8 + i) * 96 + k];
            #pragma unroll
            for (int j = 0; j < NJ; j++)
                acc[i][j] += xv.x * w0[j] + xv.y * w1[j];
        }
    }

    #pragma unroll
    for (int i = 0; i < 8; i++) {
        int r = row0 + ty * 8 + i;
        if (r < n) {
            #pragma unroll
            for (int j = 0; j < NJ; j++)
                H[(size_t)r * FOUT + tx + 32 * j] = __float2half(acc[i][j]);
        }
    }
}

// --- aggregation, F=96, fp16 source ------------------------------------------
// One wave per node. 2 lane-groups (32 lanes); active lanes li<24 each load
// uint2 = 4 fp16 (8 B). 4 edge-chains per group -> 8 edges per iteration.
// inner = sum_{s in adj(n)} dinv[s]*h_s + dinv[n]*h_n ; out = inner*dinv[n]+b.
template <bool SILU>
__global__ __launch_bounds__(256) void k_agg96(const __half* __restrict__ H,
                                               const float* __restrict__ dinv,
                                               const int* __restrict__ rowptr,
                                               const int* __restrict__ adj,
                                               const float* __restrict__ bias,
                                               float* __restrict__ OUT, int n) {
    const int l = threadIdx.x & 63;
    const int node = blockIdx.x * 4 + (threadIdx.x >> 6);
    if (node >= n) return;
    const int g = l >> 5;       // lane group 0/1
    const int li = l & 31;      // 0..23 active
    const bool act = li < 24;
    const float dn = dinv[node];
    const int e0 = rowptr[node], e1 = rowptr[node + 1];
    const uint2* __restrict__ H2 = (const uint2*)H;  // 24 uint2 per row

    float acc[4] = {0.f, 0.f, 0.f, 0.f};

    // self-loop (group 0 only)
    if (g == 0 && act) {
        uint2 u = H2[(size_t)node * 24 + li];
        float2 a = __half22float2(*(const __half2*)&u.x);
        float2 b = __half22float2(*(const __half2*)&u.y);
        acc[0] += dn * a.x; acc[1] += dn * a.y;
        acc[2] += dn * b.x; acc[3] += dn * b.y;
    }

    for (int e = e0; e < e1; e += 8) {
        // 4 chains per group: edges e+g, e+2+g, e+4+g, e+6+g
        #pragma unroll
        for (int c = 0; c < 4; ++c) {
            int ec = e + 2 * c + g;
            int ecc = ec < (e1 - 1) ? ec : (e1 - 1);  // clamp (cached dup)
            int s = adj[ecc];
            float ds = (ec < e1) ? dinv[s] : 0.f;
            if (act) {
                uint2 u = H2[(size_t)s * 24 + li];
                float2 a = __half22float2(*(const __half2*)&u.x);
                float2 b = __half22float2(*(const __half2*)&u.y);
                acc[0] += ds * a.x; acc[1] += ds * a.y;
                acc[2] += ds * b.x; acc[3] += ds * b.y;
            }
        }
    }

    // combine the two groups
    #pragma unroll
    for (int k = 0; k < 4; ++k) acc[k] += __shfl_xor(acc[k], 32, 64);

    if (l < 24) {
        float4 bv = ((const float4*)bias)[l];
        float o0 = acc[0] * dn + bv.x;
        float o1 = acc[1] * dn + bv.y;
        float o2 = acc[2] * dn + bv.z;
        float o3 = acc[3] * dn + bv.w;
        if (SILU) { o0 = silu_f(o0); o1 = silu_f(o1); o2 = silu_f(o2); o3 = silu_f(o3); }
        ((float4*)(OUT + (size_t)node * 96))[l] = make_float4(o0, o1, o2, o3);
    }
}

// --- aggregation, F=32, fp16 source ------------------------------------------
// One wave per node. 8 lane-groups of 8; each lane loads uint2 = 4 fp16.
// 2 edge-chains per group -> 16 edges per iteration.
__global__ __launch_bounds__(256) void k_agg32(const __half* __restrict__ H,
                                               const float* __restrict__ dinv,
                                               const int* __restrict__ rowptr,
                                               const int* __restrict__ adj,
                                               const float* __restrict__ bias,
                                               float* __restrict__ OUT, int n) {
    const int l = threadIdx.x & 63;
    const int node = blockIdx.x * 4 + (threadIdx.x >> 6);
    if (node >= n) return;
    const int g = l >> 3;      // 0..7
    const int li = l & 7;      // 0..7, all active
    const float dn = dinv[node];
    const int e0 = rowptr[node], e1 = rowptr[node + 1];
    const uint2* __restrict__ H2 = (const uint2*)H;  // 8 uint2 per row

    float acc[4] = {0.f, 0.f, 0.f, 0.f};

    if (g == 0) {  // self-loop
        uint2 u = H2[(size_t)node * 8 + li];
        float2 a = __half22float2(*(const __half2*)&u.x);
        float2 b = __half22float2(*(const __half2*)&u.y);
        acc[0] += dn * a.x; acc[1] += dn * a.y;
        acc[2] += dn * b.x; acc[3] += dn * b.y;
    }

    for (int e = e0; e < e1; e += 16) {
        #pragma unroll
        for (int c = 0; c < 2; ++c) {
            int ec = e + 8 * c + g;
            int ecc = ec < (e1 - 1) ? ec : (e1 - 1);
            int s = adj[ecc];
            float ds = (ec < e1) ? dinv[s] : 0.f;
            uint2 u = H2[(size_t)s * 8 + li];
            float2 a = __half22float2(*(const __half2*)&u.x);
            float2 b = __half22float2(*(const __half2*)&u.y);
            acc[0] += ds * a.x; acc[1] += ds * a.y;
            acc[2] += ds * b.x; acc[3] += ds * b.y;
        }
    }

    #pragma unroll
    for (int k = 0; k < 4; ++k) {
        acc[k] += __shfl_xor(acc[k], 8, 64);
        acc[k] += __shfl_xor(acc[k], 16, 64);
        acc[k] += __shfl_xor(acc[k], 32, 64);
    }

    if (l < 8) {
        float4 bv = ((const float4*)bias)[l];
        float4 o = make_float4(acc[0] * dn + bv.x, acc[1] * dn + bv.y,
                               acc[2] * dn + bv.z, acc[3] * dn + bv.w);
        ((float4*)(OUT + (size_t)node * 32))[l] = o;
    }
}

// --- per-graph max+mean pool (block per graph) --------------------------------
__global__ __launch_bounds__(256) void k_pool(const float* __restrict__ A,
                                              const int* __restrict__ gstart,
                                              float* __restrict__ pooled) {
    int g = blockIdx.x;
    int s0 = gstart[g], s1 = gstart[g + 1];
    int c = threadIdx.x & 31, k = threadIdx.x >> 5;
    float mx = -INFINITY, sm = 0.f;
    for (int nidx = s0 + k; nidx < s1; nidx += 8) {
        float v = A[(size_t)nidx * 32 + c];
        mx = fmaxf(mx, v);
        sm += v;
    }
    __shared__ float smx[8][32], ssm[8][32];
    smx[k][c] = mx;
    ssm[k][c] = sm;
    __syncthreads();
    if (threadIdx.x < 32) {
        float M = smx[0][c], S = ssm[0][c];
        #pragma unroll
        for (int kk = 1; kk < 8; ++kk) {
            M = fmaxf(M, smx[kk][c]);
            S += ssm[kk][c];
        }
        int cnt = s1 - s0;
        pooled[g * 64 + c] = M;
        pooled[g * 64 + 32 + c] = S / fmaxf((float)cnt, 1.0f);
    }
}

// --- row log_softmax over 64 values -------------------------------------------
__global__ __launch_bounds__(64) void k_lsm(const float* __restrict__ pooled,
                                            float* __restrict__ out) {
    int g = blockIdx.x;
    int l = threadIdx.x;
    float v = pooled[g * 64 + l];
    float m = v;
    #pragma unroll
    for (int o = 32; o > 0; o >>= 1) m = fmaxf(m, __shfl_xor(m, o, 64));
    float e = __expf(v - m);
    float s = e;
    #pragma unroll
    for (int o = 32; o > 0; o >>= 1) s += __shfl_xor(s, o, 64);
    out[g * 64 + l] = v - m - __logf(s);
}

// ---------------------------------------------------------------------------
extern "C" void kernel_launch(void* const* d_in, const int* in_sizes, int n_in,
                              void* d_out, int out_size, void* d_ws, size_t ws_size,
                              hipStream_t stream) {
    const float* x  = (const float*)d_in[0];
    const float* W0 = (const float*)d_in[1];
    const float* b0 = (const float*)d_in[2];
    const float* W1 = (const float*)d_in[3];
    const float* b1 = (const float*)d_in[4];
    const float* W2 = (const float*)d_in[5];
    const float* b2 = (const float*)d_in[6];
    const int* ei_raw    = (const int*)d_in[7];
    const int* batch_raw = (const int*)d_in[8];

    const int N = in_sizes[0] / 96;
    const int E = in_sizes[7] / 2;
    const int G = out_size / 64;
    float* out = (float*)d_out;

    char* ws = (char*)d_ws;
    size_t off = 0;
    auto alloc = [&](size_t bytes) -> void* {
        void* p = ws + off;
        off += (bytes + 255) & ~(size_t)255;
        return p;
    };
    float*  A32     = (float*)alloc((size_t)N * 96 * 4);   // agg output (fp32)
    __half* H16     = (__half*)alloc((size_t)N * 96 * 2);  // gemm out, gathered
    __half* H32_16  = (__half*)alloc((size_t)N * 32 * 2);  // layer-2 gemm out
    float*  D32     = (float*)alloc((size_t)N * 32 * 4);   // layer-2 agg out
    int*    e32     = (int*)alloc((size_t)2 * E * 4);
    int*    batch32 = (int*)alloc((size_t)N * 4);
    int*    deg     = (int*)alloc((size_t)N * 4);
    float*  dinv    = (float*)alloc((size_t)N * 4);
    int*    rowptr  = (int*)alloc((size_t)(N + 1) * 4);
    int*    cursor  = (int*)alloc((size_t)N * 4);
    int*    adj     = (int*)alloc((size_t)E * 4);
    int*    bsum    = (int*)alloc(512 * 4);
    int*    boff    = (int*)alloc(512 * 4);
    int*    flag    = (int*)alloc(256);
    int*    gstart  = (int*)alloc((size_t)(G + 1) * 4);
    float*  pooled  = (float*)alloc((size_t)G * 64 * 4);

    hipMemsetAsync(deg, 0, (size_t)N * 4, stream);
    hipMemsetAsync(cursor, 0, (size_t)N * 4, stream);

    // index dtype normalize
    k_detect<<<1, 256, 0, stream>>>(ei_raw, flag);
    k_convert<<<(2 * E + 255) / 256, 256, 0, stream>>>(ei_raw, e32, flag, 2 * E);
    k_convert<<<(N + 255) / 256, 256, 0, stream>>>(batch_raw, batch32, flag, N);

    // degrees + CSR
    k_deg<<<(E + 255) / 256, 256, 0, stream>>>(e32 + E, deg, E);
    k_dinv<<<(N + 255) / 256, 256, 0, stream>>>(deg, dinv, N);
    int NB = (N + 255) / 256;
    k_scan1<<<NB, 256, 0, stream>>>(deg, rowptr, bsum, N);
    k_scan2<<<1, 512, 0, stream>>>(bsum, boff, NB);
    k_scan3<<<NB, 256, 0, stream>>>(rowptr, boff, N, E);
    k_fill<<<(E + 255) / 256, 256, 0, stream>>>(e32, rowptr, cursor, adj, E);
    k_gstart<<<1, 256, 0, stream>>>(batch32, gstart, N, G);

    const int GB = (N + 63) / 64;
    const int AB = (N + 3) / 4;

    // layer 0
    k_gemm<96><<<GB, 256, 0, stream>>>(x, W0, H16, N);
    k_agg96<true><<<AB, 256, 0, stream>>>(H16, dinv, rowptr, adj, b0, A32, N);
    // layer 1
    k_gemm<96><<<GB, 256, 0, stream>>>(A32, W1, H16, N);
    k_agg96<true><<<AB, 256, 0, stream>>>(H16, dinv, rowptr, adj, b1, A32, N);
    // layer 2
    k_gemm<32><<<GB, 256, 0, stream>>>(A32, W2, H32_16, N);
    k_agg32<<<AB, 256, 0, stream>>>(H32_16, dinv, rowptr, adj, b2, D32, N);

    // pooling + log_softmax
    k_pool<<<G, 256, 0, stream>>>(D32, gstart, pooled);
    k_lsm<<<G, 64, 0, stream>>>(pooled, out);
}

// Round 3
// 391.178 us; speedup vs baseline: 1.3859x; 1.2329x over previous
//
#include <hip/hip_runtime.h>
#include <hip/hip_fp16.h>
#include <math.h>

// ---------------------------------------------------------------------------
// GCN: 3x (GEMM -> sym-normalized neighbor aggregate) with SiLU between,
// then per-graph max+mean pool and log_softmax.
// GEMM epilogue pre-scales rows by dinv[src] and stores fp16 ("shat" table);
// aggregation is then a pure gather-sum: out = dinv[d]*(sum shat) + b.
// 96-wide tables padded to 256B rows (2 aligned 128B lines per gather).
// ---------------------------------------------------------------------------

static __device__ __forceinline__ float silu_f(float v) {
    return v / (1.0f + __expf(-v));
}

// --- int64-vs-int32 input detection -----------------------------------------
__global__ __launch_bounds__(256) void k_detect(const int* __restrict__ raw,
                                                int* __restrict__ flag) {
    __shared__ int anynz;
    if (threadIdx.x == 0) anynz = 0;
    __syncthreads();
    if (raw[2 * threadIdx.x + 1] != 0) anynz = 1;  // benign race, same value
    __syncthreads();
    if (threadIdx.x == 0) *flag = (anynz ? 0 : 1); // 1 => int64
}

__global__ __launch_bounds__(256) void k_convert(const int* __restrict__ raw,
                                                 int* __restrict__ out,
                                                 const int* __restrict__ flag,
                                                 int count) {
    int i = blockIdx.x * 256 + threadIdx.x;
    if (i < count) out[i] = flag[0] ? raw[2 * i] : raw[i];
}

// --- degree / dinv -----------------------------------------------------------
__global__ __launch_bounds__(256) void k_deg(const int* __restrict__ dst,
                                             int* __restrict__ deg, int E) {
    int e = blockIdx.x * 256 + threadIdx.x;
    if (e < E) atomicAdd(&deg[dst[e]], 1);
}

__global__ __launch_bounds__(256) void k_dinv(const int* __restrict__ deg,
                                              float* __restrict__ dinv, int n) {
    int i = blockIdx.x * 256 + threadIdx.x;
    if (i < n) dinv[i] = rsqrtf((float)deg[i] + 1.0f);  // +1 self loop
}

// --- exclusive scan (3 kernels) ---------------------------------------------
__global__ __launch_bounds__(256) void k_scan1(const int* __restrict__ deg,
                                               int* __restrict__ rowptr,
                                               int* __restrict__ bsum, int n) {
    __shared__ int lds[256];
    int t = threadIdx.x;
    int i = blockIdx.x * 256 + t;
    int v = (i < n) ? deg[i] : 0;
    int orig = v;
    lds[t] = v;
    __syncthreads();
    for (int off = 1; off < 256; off <<= 1) {
        int y = (t >= off) ? lds[t - off] : 0;
        __syncthreads();
        lds[t] += y;
        __syncthreads();
    }
    if (i < n) rowptr[i] = lds[t] - orig;
    if (t == 255) bsum[blockIdx.x] = lds[255];
}

__global__ __launch_bounds__(512) void k_scan2(const int* __restrict__ bsum,
                                               int* __restrict__ boff, int nb) {
    __shared__ int lds[512];
    int t = threadIdx.x;
    int v = (t < nb) ? bsum[t] : 0;
    int orig = v;
    lds[t] = v;
    __syncthreads();
    for (int off = 1; off < 512; off <<= 1) {
        int y = (t >= off) ? lds[t - off] : 0;
        __syncthreads();
        lds[t] += y;
        __syncthreads();
    }
    boff[t] = lds[t] - orig;
}

__global__ __launch_bounds__(256) void k_scan3(int* __restrict__ rowptr,
                                               const int* __restrict__ boff,
                                               int n, int E) {
    int i = blockIdx.x * 256 + threadIdx.x;
    if (i < n) rowptr[i] += boff[i >> 8];
    if (i == 0) rowptr[n] = E;
}

// --- CSR fill ----------------------------------------------------------------
__global__ __launch_bounds__(256) void k_fill(const int* __restrict__ e32,
                                              const int* __restrict__ rowptr,
                                              int* __restrict__ cursor,
                                              int* __restrict__ adj, int E) {
    int e = blockIdx.x * 256 + threadIdx.x;
    if (e < E) {
        int s = e32[e];
        int d = e32[E + e];
        int p = atomicAdd(&cursor[d], 1);
        adj[rowptr[d] + p] = s;
    }
}

// --- per-graph boundaries (batch is sorted) -----------------------------------
__global__ __launch_bounds__(256) void k_gstart(const int* __restrict__ batch,
                                                int* __restrict__ gstart,
                                                int n, int G) {
    int t = threadIdx.x;
    if (t > G) return;
    int lo = 0, hi = n;
    while (lo < hi) {
        int mid = (lo + hi) >> 1;
        if (batch[mid] < t) lo = mid + 1; else hi = mid;
    }
    gstart[t] = lo;
}

// --- GEMM: H[r, :] = fp16( dinv[r] * (X[r,:96] @ W[96 x FOUT]) ) --------------
// Output row stride HSTRIDE fp16 elements (128 for FOUT=96 -> 256B rows).
template <int FOUT, int HSTRIDE>
__global__ __launch_bounds__(256) void k_gemm(const float* __restrict__ X,
                                              const float* __restrict__ W,
                                              const float* __restrict__ dinv,
                                              __half* __restrict__ H, int n) {
    __shared__ float xs[64 * 96];
    __shared__ float wsh[96 * FOUT];
    const int t = threadIdx.x;
    const int row0 = blockIdx.x * 64;

    constexpr int WQ = 96 * FOUT / 4;
    for (int q = t; q < WQ; q += 256)
        ((float4*)wsh)[q] = ((const float4*)W)[q];

    constexpr int XQ = 64 * 96 / 4;
    #pragma unroll
    for (int p = 0; p < XQ / 256; ++p) {
        int q = p * 256 + t;
        int grow = row0 + q / 24;
        float4 v = make_float4(0.f, 0.f, 0.f, 0.f);
        if (grow < n) v = ((const float4*)X)[(size_t)row0 * 24 + q];
        ((float4*)xs)[q] = v;
    }
    __syncthreads();

    const int tx = t & 31, ty = t >> 5;
    constexpr int NJ = FOUT / 32;
    float acc[8][NJ];
    #pragma unroll
    for (int i = 0; i < 8; i++)
        #pragma unroll
        for (int j = 0; j < NJ; j++) acc[i][j] = 0.f;

    for (int k = 0; k < 96; k += 2) {
        float w0[NJ], w1[NJ];
        #pragma unroll
        for (int j = 0; j < NJ; j++) {
            w0[j] = wsh[k * FOUT + tx + 32 * j];
            w1[j] = wsh[(k + 1) * FOUT + tx + 32 * j];
        }
        #pragma unroll
        for (int i = 0; i < 8; i++) {
            float2 xv = *(const float2*)&xs[(ty * 8 + i) * 96 + k];
            #pragma unroll
            for (int j = 0; j < NJ; j++)
                acc[i][j] += xv.x * w0[j] + xv.y * w1[j];
        }
    }

    #pragma unroll
    for (int i = 0; i < 8; i++) {
        int r = row0 + ty * 8 + i;
        if (r < n) {
            float dv = dinv[r];
            #pragma unroll
            for (int j = 0; j < NJ; j++)
                H[(size_t)r * HSTRIDE + tx + 32 * j] = __float2half(acc[i][j] * dv);
        }
    }
}

// --- aggregation, F=96 (rows padded to 128 fp16 = 256B) -----------------------
// One wave per node. Half h = l>>5 (2 rows per gather instr), li = l&31 owns
// features 4*li..4*li+3 (li<24 real, li>=24 padding -> discarded).
// 16 edges per iteration: 1 coalesced adj load + 8 row-gather instructions.
template <bool SILU>
__global__ __launch_bounds__(256) void k_agg96(const __half* __restrict__ Hp,
                                               const float* __restrict__ dinv,
                                               const int* __restrict__ rowptr,
                                               const int* __restrict__ adj,
                                               const float* __restrict__ bias,
                                               float* __restrict__ OUT, int n) {
    const int l = threadIdx.x & 63;
    const int node = blockIdx.x * 4 + (threadIdx.x >> 6);
    if (node >= n) return;
    const int h = l >> 5;
    const int li = l & 31;
    const float dn = dinv[node];
    const int e0 = rowptr[node], e1 = rowptr[node + 1];
    const uint2* __restrict__ H2 = (const uint2*)Hp;  // 32 uint2 per row

    float acc[4] = {0.f, 0.f, 0.f, 0.f};

    // self row (counted once, in half 0)
    {
        uint2 u = H2[(size_t)node * 32 + li];
        float ws = (h == 0) ? 1.f : 0.f;
        float2 a = __half22float2(*(const __half2*)&u.x);
        float2 b = __half22float2(*(const __half2*)&u.y);
        acc[0] = fmaf(ws, a.x, acc[0]); acc[1] = fmaf(ws, a.y, acc[1]);
        acc[2] = fmaf(ws, b.x, acc[2]); acc[3] = fmaf(ws, b.y, acc[3]);
    }

    for (int e = e0; e < e1; e += 16) {
        int ai = e + (l & 15);
        int aic = ai < e1 ? ai : e1 - 1;
        int v_s = adj[aic];               // one coalesced load: 16 edge srcs
        #pragma unroll
        for (int j = 0; j < 8; ++j) {
            int c = 2 * j + h;            // chain id 0..15, halves interleave
            int s = __shfl(v_s, c, 64);
            uint2 u = H2[(size_t)s * 32 + li];
            float w = (e + c < e1) ? 1.f : 0.f;
            float2 a = __half22float2(*(const __half2*)&u.x);
            float2 b = __half22float2(*(const __half2*)&u.y);
            acc[0] = fmaf(w, a.x, acc[0]); acc[1] = fmaf(w, a.y, acc[1]);
            acc[2] = fmaf(w, b.x, acc[2]); acc[3] = fmaf(w, b.y, acc[3]);
        }
    }

    #pragma unroll
    for (int k = 0; k < 4; ++k) acc[k] += __shfl_xor(acc[k], 32, 64);

    if (l < 24) {
        float4 bv = ((const float4*)bias)[l];
        float o0 = acc[0] * dn + bv.x;
        float o1 = acc[1] * dn + bv.y;
        float o2 = acc[2] * dn + bv.z;
        float o3 = acc[3] * dn + bv.w;
        if (SILU) { o0 = silu_f(o0); o1 = silu_f(o1); o2 = silu_f(o2); o3 = silu_f(o3); }
        ((float4*)(OUT + (size_t)node * 96))[l] = make_float4(o0, o1, o2, o3);
    }
}

// --- aggregation, F=32 (rows packed 64B) --------------------------------------
// Quarter q = l>>4 (4 rows per gather instr), li = l&15 owns feats 2li,2li+1.
__global__ __launch_bounds__(256) void k_agg32(const __half* __restrict__ Hp,
                                               const float* __restrict__ dinv,
                                               const int* __restrict__ rowptr,
                                               const int* __restrict__ adj,
                                               const float* __restrict__ bias,
                                               float* __restrict__ OUT, int n) {
    const int l = threadIdx.x & 63;
    const int node = blockIdx.x * 4 + (threadIdx.x >> 6);
    if (node >= n) return;
    const int q = l >> 4;
    const int li = l & 15;
    const float dn = dinv[node];
    const int e0 = rowptr[node], e1 = rowptr[node + 1];
    const unsigned* __restrict__ H1 = (const unsigned*)Hp;  // 16 u32 per row

    float acc[2] = {0.f, 0.f};

    {
        unsigned u = H1[(size_t)node * 16 + li];
        float ws = (q == 0) ? 1.f : 0.f;
        float2 a = __half22float2(*(const __half2*)&u);
        acc[0] = fmaf(ws, a.x, acc[0]); acc[1] = fmaf(ws, a.y, acc[1]);
    }

    for (int e = e0; e < e1; e += 16) {
        int ai = e + (l & 15);
        int aic = ai < e1 ? ai : e1 - 1;
        int v_s = adj[aic];
        #pragma unroll
        for (int j = 0; j < 4; ++j) {
            int c = 4 * j + q;
            int s = __shfl(v_s, c, 64);
            unsigned u = H1[(size_t)s * 16 + li];
            float w = (e + c < e1) ? 1.f : 0.f;
            float2 a = __half22float2(*(const __half2*)&u);
            acc[0] = fmaf(w, a.x, acc[0]); acc[1] = fmaf(w, a.y, acc[1]);
        }
    }

    #pragma unroll
    for (int k = 0; k < 2; ++k) {
        acc[k] += __shfl_xor(acc[k], 16, 64);
        acc[k] += __shfl_xor(acc[k], 32, 64);
    }

    if (l < 16) {
        float2 bv = ((const float2*)bias)[l];
        float2 o = make_float2(acc[0] * dn + bv.x, acc[1] * dn + bv.y);
        ((float2*)(OUT + (size_t)node * 32))[l] = o;
    }
}

// --- per-graph max+mean pool (block per graph) --------------------------------
__global__ __launch_bounds__(256) void k_pool(const float* __restrict__ A,
                                              const int* __restrict__ gstart,
                                              float* __restrict__ pooled) {
    int g = blockIdx.x;
    int s0 = gstart[g], s1 = gstart[g + 1];
    int c = threadIdx.x & 31, k = threadIdx.x >> 5;
    float mx = -INFINITY, sm = 0.f;
    for (int nidx = s0 + k; nidx < s1; nidx += 8) {
        float v = A[(size_t)nidx * 32 + c];
        mx = fmaxf(mx, v);
        sm += v;
    }
    __shared__ float smx[8][32], ssm[8][32];
    smx[k][c] = mx;
    ssm[k][c] = sm;
    __syncthreads();
    if (threadIdx.x < 32) {
        float M = smx[0][c], S = ssm[0][c];
        #pragma unroll
        for (int kk = 1; kk < 8; ++kk) {
            M = fmaxf(M, smx[kk][c]);
            S += ssm[kk][c];
        }
        int cnt = s1 - s0;
        pooled[g * 64 + c] = M;
        pooled[g * 64 + 32 + c] = S / fmaxf((float)cnt, 1.0f);
    }
}

// --- row log_softmax over 64 values -------------------------------------------
__global__ __launch_bounds__(64) void k_lsm(const float* __restrict__ pooled,
                                            float* __restrict__ out) {
    int g = blockIdx.x;
    int l = threadIdx.x;
    float v = pooled[g * 64 + l];
    float m = v;
    #pragma unroll
    for (int o = 32; o > 0; o >>= 1) m = fmaxf(m, __shfl_xor(m, o, 64));
    float e = __expf(v - m);
    float s = e;
    #pragma unroll
    for (int o = 32; o > 0; o >>= 1) s += __shfl_xor(s, o, 64);
    out[g * 64 + l] = v - m - __logf(s);
}

// ---------------------------------------------------------------------------
extern "C" void kernel_launch(void* const* d_in, const int* in_sizes, int n_in,
                              void* d_out, int out_size, void* d_ws, size_t ws_size,
                              hipStream_t stream) {
    const float* x  = (const float*)d_in[0];
    const float* W0 = (const float*)d_in[1];
    const float* b0 = (const float*)d_in[2];
    const float* W1 = (const float*)d_in[3];
    const float* b1 = (const float*)d_in[4];
    const float* W2 = (const float*)d_in[5];
    const float* b2 = (const float*)d_in[6];
    const int* ei_raw    = (const int*)d_in[7];
    const int* batch_raw = (const int*)d_in[8];

    const int N = in_sizes[0] / 96;
    const int E = in_sizes[7] / 2;
    const int G = out_size / 64;
    float* out = (float*)d_out;

    char* ws = (char*)d_ws;
    size_t off = 0;
    auto alloc = [&](size_t bytes) -> void* {
        void* p = ws + off;
        off += (bytes + 255) & ~(size_t)255;
        return p;
    };
    float*  A32     = (float*)alloc((size_t)N * 96 * 4);    // agg output (fp32)
    __half* Hp96    = (__half*)alloc((size_t)N * 128 * 2);  // shat, 256B rows
    __half* Hp32    = (__half*)alloc((size_t)N * 32 * 2);   // layer-2 shat, 64B rows
    float*  D32     = (float*)alloc((size_t)N * 32 * 4);    // layer-2 agg out
    int*    e32     = (int*)alloc((size_t)2 * E * 4);
    int*    batch32 = (int*)alloc((size_t)N * 4);
    int*    deg     = (int*)alloc((size_t)N * 4);
    float*  dinv    = (float*)alloc((size_t)N * 4);
    int*    rowptr  = (int*)alloc((size_t)(N + 1) * 4);
    int*    cursor  = (int*)alloc((size_t)N * 4);
    int*    adj     = (int*)alloc((size_t)E * 4);
    int*    bsum    = (int*)alloc(512 * 4);
    int*    boff    = (int*)alloc(512 * 4);
    int*    flag    = (int*)alloc(256);
    int*    gstart  = (int*)alloc((size_t)(G + 1) * 4);
    float*  pooled  = (float*)alloc((size_t)G * 64 * 4);

    hipMemsetAsync(deg, 0, (size_t)N * 4, stream);
    hipMemsetAsync(cursor, 0, (size_t)N * 4, stream);

    // index dtype normalize
    k_detect<<<1, 256, 0, stream>>>(ei_raw, flag);
    k_convert<<<(2 * E + 255) / 256, 256, 0, stream>>>(ei_raw, e32, flag, 2 * E);
    k_convert<<<(N + 255) / 256, 256, 0, stream>>>(batch_raw, batch32, flag, N);

    // degrees + CSR
    k_deg<<<(E + 255) / 256, 256, 0, stream>>>(e32 + E, deg, E);
    k_dinv<<<(N + 255) / 256, 256, 0, stream>>>(deg, dinv, N);
    int NB = (N + 255) / 256;
    k_scan1<<<NB, 256, 0, stream>>>(deg, rowptr, bsum, N);
    k_scan2<<<1, 512, 0, stream>>>(bsum, boff, NB);
    k_scan3<<<NB, 256, 0, stream>>>(rowptr, boff, N, E);
    k_fill<<<(E + 255) / 256, 256, 0, stream>>>(e32, rowptr, cursor, adj, E);
    k_gstart<<<1, 256, 0, stream>>>(batch32, gstart, N, G);

    const int GB = (N + 63) / 64;
    const int AB = (N + 3) / 4;

    // layer 0
    k_gemm<96, 128><<<GB, 256, 0, stream>>>(x, W0, dinv, Hp96, N);
    k_agg96<true><<<AB, 256, 0, stream>>>(Hp96, dinv, rowptr, adj, b0, A32, N);
    // layer 1
    k_gemm<96, 128><<<GB, 256, 0, stream>>>(A32, W1, dinv, Hp96, N);
    k_agg96<true><<<AB, 256, 0, stream>>>(Hp96, dinv, rowptr, adj, b1, A32, N);
    // layer 2
    k_gemm<32, 32><<<GB, 256, 0, stream>>>(A32, W2, dinv, Hp32, N);
    k_agg32<<<AB, 256, 0, stream>>>(Hp32, dinv, rowptr, adj, b2, D32, N);

    // pooling + log_softmax
    k_pool<<<G, 256, 0, stream>>>(D32, gstart, pooled);
    k_lsm<<<G, 64, 0, stream>>>(pooled, out);
}

// Round 4
// 305.749 us; speedup vs baseline: 1.7732x; 1.2794x over previous
//
#include <hip/hip_runtime.h>
#include <hip/hip_fp16.h>
#include <math.h>

// ---------------------------------------------------------------------------
// GCN: 3x (MFMA-fp16 GEMM -> sym-normalized neighbor aggregate) with SiLU,
// then per-graph max+mean pool and log_softmax.
// GEMM: D = X @ W via v_mfma_f32_16x16x32_f16, LDS-free:
//   A-frags straight from global X rows (fp32 -> cvt), B-frags from
//   pre-transposed fp16 W^T. A and B use the IDENTICAL per-lane k-addressing,
//   so the k->slot hardware map cancels (dot products are k-permutation
//   invariant). C/D map (verified m89): col=lane&15, row=(lane>>4)*4+reg.
// GEMM epilogue pre-scales rows by dinv[src], stores fp16 "shat" table
// (96-wide padded to 256B rows); agg = pure gather-sum * dinv[d] + b.
// ---------------------------------------------------------------------------

typedef _Float16 f16x8 __attribute__((ext_vector_type(8)));
typedef float f32x4 __attribute__((ext_vector_type(4)));

static __device__ __forceinline__ float silu_f(float v) {
    return v / (1.0f + __expf(-v));
}

// --- int64-vs-int32 input detection -----------------------------------------
__global__ __launch_bounds__(256) void k_detect(const int* __restrict__ raw,
                                                int* __restrict__ flag) {
    __shared__ int anynz;
    if (threadIdx.x == 0) anynz = 0;
    __syncthreads();
    if (raw[2 * threadIdx.x + 1] != 0) anynz = 1;  // benign race, same value
    __syncthreads();
    if (threadIdx.x == 0) *flag = (anynz ? 0 : 1); // 1 => int64
}

__global__ __launch_bounds__(256) void k_convert(const int* __restrict__ raw,
                                                 int* __restrict__ out,
                                                 const int* __restrict__ flag,
                                                 int count) {
    int i = blockIdx.x * 256 + threadIdx.x;
    if (i < count) out[i] = flag[0] ? raw[2 * i] : raw[i];
}

// --- degree / dinv -----------------------------------------------------------
__global__ __launch_bounds__(256) void k_deg(const int* __restrict__ dst,
                                             int* __restrict__ deg, int E) {
    int e = blockIdx.x * 256 + threadIdx.x;
    if (e < E) atomicAdd(&deg[dst[e]], 1);
}

__global__ __launch_bounds__(256) void k_dinv(const int* __restrict__ deg,
                                              float* __restrict__ dinv, int n) {
    int i = blockIdx.x * 256 + threadIdx.x;
    if (i < n) dinv[i] = rsqrtf((float)deg[i] + 1.0f);  // +1 self loop
}

// --- exclusive scan (3 kernels) ---------------------------------------------
__global__ __launch_bounds__(256) void k_scan1(const int* __restrict__ deg,
                                               int* __restrict__ rowptr,
                                               int* __restrict__ bsum, int n) {
    __shared__ int lds[256];
    int t = threadIdx.x;
    int i = blockIdx.x * 256 + t;
    int v = (i < n) ? deg[i] : 0;
    int orig = v;
    lds[t] = v;
    __syncthreads();
    for (int off = 1; off < 256; off <<= 1) {
        int y = (t >= off) ? lds[t - off] : 0;
        __syncthreads();
        lds[t] += y;
        __syncthreads();
    }
    if (i < n) rowptr[i] = lds[t] - orig;
    if (t == 255) bsum[blockIdx.x] = lds[255];
}

__global__ __launch_bounds__(512) void k_scan2(const int* __restrict__ bsum,
                                               int* __restrict__ boff, int nb) {
    __shared__ int lds[512];
    int t = threadIdx.x;
    int v = (t < nb) ? bsum[t] : 0;
    int orig = v;
    lds[t] = v;
    __syncthreads();
    for (int off = 1; off < 512; off <<= 1) {
        int y = (t >= off) ? lds[t - off] : 0;
        __syncthreads();
        lds[t] += y;
        __syncthreads();
    }
    boff[t] = lds[t] - orig;
}

__global__ __launch_bounds__(256) void k_scan3(int* __restrict__ rowptr,
                                               const int* __restrict__ boff,
                                               int n, int E) {
    int i = blockIdx.x * 256 + threadIdx.x;
    if (i < n) rowptr[i] += boff[i >> 8];
    if (i == 0) rowptr[n] = E;
}

// --- CSR fill ----------------------------------------------------------------
__global__ __launch_bounds__(256) void k_fill(const int* __restrict__ e32,
                                              const int* __restrict__ rowptr,
                                              int* __restrict__ cursor,
                                              int* __restrict__ adj, int E) {
    int e = blockIdx.x * 256 + threadIdx.x;
    if (e < E) {
        int s = e32[e];
        int d = e32[E + e];
        int p = atomicAdd(&cursor[d], 1);
        adj[rowptr[d] + p] = s;
    }
}

// --- per-graph boundaries (batch is sorted) -----------------------------------
__global__ __launch_bounds__(256) void k_gstart(const int* __restrict__ batch,
                                                int* __restrict__ gstart,
                                                int n, int G) {
    int t = threadIdx.x;
    if (t > G) return;
    int lo = 0, hi = n;
    while (lo < hi) {
        int mid = (lo + hi) >> 1;
        if (batch[mid] < t) lo = mid + 1; else hi = mid;
    }
    gstart[t] = lo;
}

// --- W transpose + fp16 convert: WT[n][k] = fp16(W[k][n]) ---------------------
__global__ __launch_bounds__(256) void k_wt(const float* __restrict__ W,
                                            __half* __restrict__ WT, int fout) {
    int idx = blockIdx.x * 256 + threadIdx.x;
    if (idx < fout * 96) {
        int nn = idx / 96, kk = idx - nn * 96;
        WT[idx] = __float2half(W[kk * fout + nn]);
    }
}

// --- MFMA GEMM: H[r,:] = fp16( dinv[r] * (X[r,:96] @ W) ), LDS-free ----------
// Block = 4 waves; wave w owns rows blockIdx*64 + 16w .. +15.
// NT = FOUT/16 col-tiles; 3 K-chunks of 32.
template <int FOUT, int HSTRIDE>
__global__ __launch_bounds__(256) void k_gemm_mfma(const float* __restrict__ X,
                                                   const __half* __restrict__ WT,
                                                   const float* __restrict__ dinv,
                                                   __half* __restrict__ H, int n) {
    const int l = threadIdx.x & 63;
    const int w = threadIdx.x >> 6;
    const int row0 = blockIdx.x * 64 + w * 16;
    const int lr = l & 15, lg = l >> 4;
    constexpr int NT = FOUT / 16;

    // B fragments (W^T rows, L2-hot): same per-lane k-addressing as A below.
    f16x8 bfrag[NT][3];
    #pragma unroll
    for (int t = 0; t < NT; ++t)
        #pragma unroll
        for (int kk = 0; kk < 3; ++kk)
            bfrag[t][kk] = *(const f16x8*)&WT[(t * 16 + lr) * 96 + kk * 32 + lg * 8];

    f32x4 acc[NT];
    #pragma unroll
    for (int t = 0; t < NT; ++t) acc[t] = (f32x4){0.f, 0.f, 0.f, 0.f};

    int arow = row0 + lr;
    int arow_c = arow < n ? arow : n - 1;  // clamp: garbage stays in rows >= n
    const float* xr = X + (size_t)arow_c * 96;

    #pragma unroll
    for (int kk = 0; kk < 3; ++kk) {
        float4 u0 = *(const float4*)&xr[kk * 32 + lg * 8];
        float4 u1 = *(const float4*)&xr[kk * 32 + lg * 8 + 4];
        f16x8 af;
        af[0] = (_Float16)u0.x; af[1] = (_Float16)u0.y;
        af[2] = (_Float16)u0.z; af[3] = (_Float16)u0.w;
        af[4] = (_Float16)u1.x; af[5] = (_Float16)u1.y;
        af[6] = (_Float16)u1.z; af[7] = (_Float16)u1.w;
        #pragma unroll
        for (int t = 0; t < NT; ++t)
            acc[t] = __builtin_amdgcn_mfma_f32_16x16x32_f16(af, bfrag[t][kk], acc[t], 0, 0, 0);
    }

    // C/D: col = t*16 + lr, row = row0 + lg*4 + i  (m89-verified map)
    #pragma unroll
    for (int i = 0; i < 4; ++i) {
        int r = row0 + lg * 4 + i;
        if (r < n) {
            float dv = dinv[r];
            #pragma unroll
            for (int t = 0; t < NT; ++t)
                H[(size_t)r * HSTRIDE + t * 16 + lr] = __float2half(acc[t][i] * dv);
        }
    }
}

// --- aggregation, F=96 (rows padded to 128 fp16 = 256B) -----------------------
template <bool SILU>
__global__ __launch_bounds__(256) void k_agg96(const __half* __restrict__ Hp,
                                               const float* __restrict__ dinv,
                                               const int* __restrict__ rowptr,
                                               const int* __restrict__ adj,
                                               const float* __restrict__ bias,
                                               float* __restrict__ OUT, int n) {
    const int l = threadIdx.x & 63;
    const int node = blockIdx.x * 4 + (threadIdx.x >> 6);
    if (node >= n) return;
    const int h = l >> 5;
    const int li = l & 31;
    const float dn = dinv[node];
    const int e0 = rowptr[node], e1 = rowptr[node + 1];
    const uint2* __restrict__ H2 = (const uint2*)Hp;  // 32 uint2 per row

    float acc[4] = {0.f, 0.f, 0.f, 0.f};

    {
        uint2 u = H2[(size_t)node * 32 + li];
        float ws = (h == 0) ? 1.f : 0.f;
        float2 a = __half22float2(*(const __half2*)&u.x);
        float2 b = __half22float2(*(const __half2*)&u.y);
        acc[0] = fmaf(ws, a.x, acc[0]); acc[1] = fmaf(ws, a.y, acc[1]);
        acc[2] = fmaf(ws, b.x, acc[2]); acc[3] = fmaf(ws, b.y, acc[3]);
    }

    for (int e = e0; e < e1; e += 16) {
        int ai = e + (l & 15);
        int aic = ai < e1 ? ai : e1 - 1;
        int v_s = adj[aic];
        #pragma unroll
        for (int j = 0; j < 8; ++j) {
            int c = 2 * j + h;
            int s = __shfl(v_s, c, 64);
            uint2 u = H2[(size_t)s * 32 + li];
            float w2 = (e + c < e1) ? 1.f : 0.f;
            float2 a = __half22float2(*(const __half2*)&u.x);
            float2 b = __half22float2(*(const __half2*)&u.y);
            acc[0] = fmaf(w2, a.x, acc[0]); acc[1] = fmaf(w2, a.y, acc[1]);
            acc[2] = fmaf(w2, b.x, acc[2]); acc[3] = fmaf(w2, b.y, acc[3]);
        }
    }

    #pragma unroll
    for (int k = 0; k < 4; ++k) acc[k] += __shfl_xor(acc[k], 32, 64);

    if (l < 24) {
        float4 bv = ((const float4*)bias)[l];
        float o0 = acc[0] * dn + bv.x;
        float o1 = acc[1] * dn + bv.y;
        float o2 = acc[2] * dn + bv.z;
        float o3 = acc[3] * dn + bv.w;
        if (SILU) { o0 = silu_f(o0); o1 = silu_f(o1); o2 = silu_f(o2); o3 = silu_f(o3); }
        ((float4*)(OUT + (size_t)node * 96))[l] = make_float4(o0, o1, o2, o3);
    }
}

// --- aggregation, F=32 (rows packed 64B) --------------------------------------
__global__ __launch_bounds__(256) void k_agg32(const __half* __restrict__ Hp,
                                               const float* __restrict__ dinv,
                                               const int* __restrict__ rowptr,
                                               const int* __restrict__ adj,
                                               const float* __restrict__ bias,
                                               float* __restrict__ OUT, int n) {
    const int l = threadIdx.x & 63;
    const int node = blockIdx.x * 4 + (threadIdx.x >> 6);
    if (node >= n) return;
    const int q = l >> 4;
    const int li = l & 15;
    const float dn = dinv[node];
    const int e0 = rowptr[node], e1 = rowptr[node + 1];
    const unsigned* __restrict__ H1 = (const unsigned*)Hp;  // 16 u32 per row

    float acc[2] = {0.f, 0.f};

    {
        unsigned u = H1[(size_t)node * 16 + li];
        float ws = (q == 0) ? 1.f : 0.f;
        float2 a = __half22float2(*(const __half2*)&u);
        acc[0] = fmaf(ws, a.x, acc[0]); acc[1] = fmaf(ws, a.y, acc[1]);
    }

    for (int e = e0; e < e1; e += 16) {
        int ai = e + (l & 15);
        int aic = ai < e1 ? ai : e1 - 1;
        int v_s = adj[aic];
        #pragma unroll
        for (int j = 0; j < 4; ++j) {
            int c = 4 * j + q;
            int s = __shfl(v_s, c, 64);
            unsigned u = H1[(size_t)s * 16 + li];
            float w2 = (e + c < e1) ? 1.f : 0.f;
            float2 a = __half22float2(*(const __half2*)&u);
            acc[0] = fmaf(w2, a.x, acc[0]); acc[1] = fmaf(w2, a.y, acc[1]);
        }
    }

    #pragma unroll
    for (int k = 0; k < 2; ++k) {
        acc[k] += __shfl_xor(acc[k], 16, 64);
        acc[k] += __shfl_xor(acc[k], 32, 64);
    }

    if (l < 16) {
        float2 bv = ((const float2*)bias)[l];
        float2 o = make_float2(acc[0] * dn + bv.x, acc[1] * dn + bv.y);
        ((float2*)(OUT + (size_t)node * 32))[l] = o;
    }
}

// --- per-graph max+mean pool (block per graph) --------------------------------
__global__ __launch_bounds__(256) void k_pool(const float* __restrict__ A,
                                              const int* __restrict__ gstart,
                                              float* __restrict__ pooled) {
    int g = blockIdx.x;
    int s0 = gstart[g], s1 = gstart[g + 1];
    int c = threadIdx.x & 31, k = threadIdx.x >> 5;
    float mx = -INFINITY, sm = 0.f;
    for (int nidx = s0 + k; nidx < s1; nidx += 8) {
        float v = A[(size_t)nidx * 32 + c];
        mx = fmaxf(mx, v);
        sm += v;
    }
    __shared__ float smx[8][32], ssm[8][32];
    smx[k][c] = mx;
    ssm[k][c] = sm;
    __syncthreads();
    if (threadIdx.x < 32) {
        float M = smx[0][c], S = ssm[0][c];
        #pragma unroll
        for (int kk = 1; kk < 8; ++kk) {
            M = fmaxf(M, smx[kk][c]);
            S += ssm[kk][c];
        }
        int cnt = s1 - s0;
        pooled[g * 64 + c] = M;
        pooled[g * 64 + 32 + c] = S / fmaxf((float)cnt, 1.0f);
    }
}

// --- row log_softmax over 64 values -------------------------------------------
__global__ __launch_bounds__(64) void k_lsm(const float* __restrict__ pooled,
                                            float* __restrict__ out) {
    int g = blockIdx.x;
    int l = threadIdx.x;
    float v = pooled[g * 64 + l];
    float m = v;
    #pragma unroll
    for (int o = 32; o > 0; o >>= 1) m = fmaxf(m, __shfl_xor(m, o, 64));
    float e = __expf(v - m);
    float s = e;
    #pragma unroll
    for (int o = 32; o > 0; o >>= 1) s += __shfl_xor(s, o, 64);
    out[g * 64 + l] = v - m - __logf(s);
}

// ---------------------------------------------------------------------------
extern "C" void kernel_launch(void* const* d_in, const int* in_sizes, int n_in,
                              void* d_out, int out_size, void* d_ws, size_t ws_size,
                              hipStream_t stream) {
    const float* x  = (const float*)d_in[0];
    const float* W0 = (const float*)d_in[1];
    const float* b0 = (const float*)d_in[2];
    const float* W1 = (const float*)d_in[3];
    const float* b1 = (const float*)d_in[4];
    const float* W2 = (const float*)d_in[5];
    const float* b2 = (const float*)d_in[6];
    const int* ei_raw    = (const int*)d_in[7];
    const int* batch_raw = (const int*)d_in[8];

    const int N = in_sizes[0] / 96;
    const int E = in_sizes[7] / 2;
    const int G = out_size / 64;
    float* out = (float*)d_out;

    char* ws = (char*)d_ws;
    size_t off = 0;
    auto alloc = [&](size_t bytes) -> void* {
        void* p = ws + off;
        off += (bytes + 255) & ~(size_t)255;
        return p;
    };
    float*  A32     = (float*)alloc((size_t)N * 96 * 4);    // agg output (fp32)
    __half* Hp96    = (__half*)alloc((size_t)N * 128 * 2);  // shat, 256B rows
    __half* Hp32    = (__half*)alloc((size_t)N * 32 * 2);   // layer-2 shat, 64B rows
    float*  D32     = (float*)alloc((size_t)N * 32 * 4);    // layer-2 agg out
    int*    e32     = (int*)alloc((size_t)2 * E * 4);
    int*    batch32 = (int*)alloc((size_t)N * 4);
    int*    deg     = (int*)alloc((size_t)N * 4);
    float*  dinv    = (float*)alloc((size_t)N * 4);
    int*    rowptr  = (int*)alloc((size_t)(N + 1) * 4);
    int*    cursor  = (int*)alloc((size_t)N * 4);
    int*    adj     = (int*)alloc((size_t)E * 4);
    int*    bsum    = (int*)alloc(512 * 4);
    int*    boff    = (int*)alloc(512 * 4);
    int*    flag    = (int*)alloc(256);
    int*    gstart  = (int*)alloc((size_t)(G + 1) * 4);
    float*  pooled  = (float*)alloc((size_t)G * 64 * 4);
    __half* WT0     = (__half*)alloc((size_t)96 * 96 * 2);  // W^T fp16
    __half* WT1     = (__half*)alloc((size_t)96 * 96 * 2);
    __half* WT2     = (__half*)alloc((size_t)32 * 96 * 2);

    hipMemsetAsync(deg, 0, (size_t)N * 4, stream);
    hipMemsetAsync(cursor, 0, (size_t)N * 4, stream);

    // index dtype normalize
    k_detect<<<1, 256, 0, stream>>>(ei_raw, flag);
    k_convert<<<(2 * E + 255) / 256, 256, 0, stream>>>(ei_raw, e32, flag, 2 * E);
    k_convert<<<(N + 255) / 256, 256, 0, stream>>>(batch_raw, batch32, flag, N);

    // weight transpose+convert (tiny)
    k_wt<<<(96 * 96 + 255) / 256, 256, 0, stream>>>(W0, WT0, 96);
    k_wt<<<(96 * 96 + 255) / 256, 256, 0, stream>>>(W1, WT1, 96);
    k_wt<<<(32 * 96 + 255) / 256, 256, 0, stream>>>(W2, WT2, 32);

    // degrees + CSR
    k_deg<<<(E + 255) / 256, 256, 0, stream>>>(e32 + E, deg, E);
    k_dinv<<<(N + 255) / 256, 256, 0, stream>>>(deg, dinv, N);
    int NB = (N + 255) / 256;
    k_scan1<<<NB, 256, 0, stream>>>(deg, rowptr, bsum, N);
    k_scan2<<<1, 512, 0, stream>>>(bsum, boff, NB);
    k_scan3<<<NB, 256, 0, stream>>>(rowptr, boff, N, E);
    k_fill<<<(E + 255) / 256, 256, 0, stream>>>(e32, rowptr, cursor, adj, E);
    k_gstart<<<1, 256, 0, stream>>>(batch32, gstart, N, G);

    const int GB = (N + 63) / 64;
    const int AB = (N + 3) / 4;

    // layer 0
    k_gemm_mfma<96, 128><<<GB, 256, 0, stream>>>(x, WT0, dinv, Hp96, N);
    k_agg96<true><<<AB, 256, 0, stream>>>(Hp96, dinv, rowptr, adj, b0, A32, N);
    // layer 1
    k_gemm_mfma<96, 128><<<GB, 256, 0, stream>>>(A32, WT1, dinv, Hp96, N);
    k_agg96<true><<<AB, 256, 0, stream>>>(Hp96, dinv, rowptr, adj, b1, A32, N);
    // layer 2
    k_gemm_mfma<32, 32><<<GB, 256, 0, stream>>>(A32, WT2, dinv, Hp32, N);
    k_agg32<<<AB, 256, 0, stream>>>(Hp32, dinv, rowptr, adj, b2, D32, N);

    // pooling + log_softmax
    k_pool<<<G, 256, 0, stream>>>(D32, gstart, pooled);
    k_lsm<<<G, 64, 0, stream>>>(pooled, out);
}